// Round 8
// baseline (46.984 us; speedup 1.0000x reference)
//
#include <hip/hip_runtime.h>
#include <hip/hip_bf16.h>

// TT-Rec embedding bag, MI355X. R7 version (= R6 + NULL-row zeroing fix).
// P=(100,100,100), Q=(4,4,8), R=(1,32,32,1), D=128, B=4096, H=50, n=204800.
//
//   AB table split into TWO half-tables (m 0..7 / 8..15), 512 B rows, 5.12 MB
//   each. Pool blocks XCD-steered: XCD 0-3 -> half 0, XCD 4-7 -> half 1, so
//   each XCD's L2 sees only a 5.12 MB working set (vs 10.24 before).
//   Each MFMA packs TWO indices (A rows 0-7 = idx j, rows 8-15 = idx j+1;
//   B cols 0-7 = c(i3_j), cols 8-15 = c(i3_{j+1})); lane bit 3 selects.
//   Halves combine into out via f32 atomicAdd onto a memset-zeroed buffer.

#define P0 100
#define P1 100
#define P2 100
#define Q2 8
#define DIM 128
#define NPAIR (P0 * P1)
#define NULL_BFO (P2 * 512)          // zeroed bfrag row (byte offset)

typedef __attribute__((ext_vector_type(8))) short short8v;   // 8 bf16
typedef __attribute__((ext_vector_type(4))) float f32x4;

__device__ inline short f2bf(float x) {
    union { __hip_bfloat16 h; short s; } u;
    u.h = __float2bfloat16(x);
    return u.s;
}

// ---------------- K1: fused prep ----------------
__global__ __launch_bounds__(256) void prep(const int* __restrict__ lengths, int B,
                                            const float* __restrict__ core0,
                                            const float* __restrict__ core1,
                                            const float* __restrict__ core2,
                                            int* __restrict__ offsets,
                                            __hip_bfloat16* __restrict__ bfrag,
                                            __hip_bfloat16* __restrict__ ab0,
                                            __hip_bfloat16* __restrict__ ab1) {
    int bid = blockIdx.x;
    int t = threadIdx.x;
    if (bid == 0) {
        // ---- zero the null bfrag row (512 B = 256 shorts; FIXED indexing) ----
        ((short*)bfrag)[P2 * 256 + t] = 0;
        // ---- exclusive scan of lengths (single block, 256 threads) ----
        __shared__ int part[256];
        int per = (B + 255) / 256;
        int s = 0;
        for (int k = 0; k < per; ++k) {
            int i = t * per + k;
            s += (i < B) ? lengths[i] : 0;
        }
        part[t] = s;
        __syncthreads();
        for (int d = 1; d < 256; d <<= 1) {
            int v = (t >= d) ? part[t - d] : 0;
            __syncthreads();
            part[t] += v;
            __syncthreads();
        }
        int run = part[t] - s;
        for (int k = 0; k < per; ++k) {
            int i = t * per + k;
            if (i < B) { offsets[i] = run; run += lengths[i]; }
        }
        if (t == 255) offsets[B] = part[255];
    } else if (bid <= P2) {
        // ---- bfrag prepack: lane l holds C[k=(l>>4)*8+j][col=l&15],
        // cols 8..15 duplicate 0..7; stored: i3*256 + (l>>4)*64 + (l&7)*8 + j
        if (t < 64 && !(t & 8)) {
            int i3 = bid - 1;
            int h = t >> 4, c3 = t & 7;
            const float* crow = core2 + (size_t)i3 * (32 * Q2);
            __hip_bfloat16* o = bfrag + (size_t)i3 * 256 + h * 64 + c3 * 8;
#pragma unroll
            for (int j = 0; j < 8; ++j)
                o[j] = __float2bfloat16(crow[(h * 8 + j) * Q2 + c3]);
        }
    } else {
        // ---- AB build via MFMA: g in [0,200): i2 = g>>1, wave ct = (g&1)*4+w ----
        int g = bid - 1 - P2;
        int i2 = g >> 1;
        int w = t >> 6, lane = t & 63;
        int ct = (g & 1) * 4 + w;            // 0..7 (column tile of 16)
        int h = lane >> 4;                   // k-half (0..3) -> k = h*8+j
        int c16 = lane & 15;

        // B-frag once per wave: B[k][col] = core1[i2][k*128 + col], col = ct*16+c16
        const float* bbase = core1 + (size_t)i2 * 4096 + (h * 8) * 128 + ct * 16 + c16;
        short8v bfr;
#pragma unroll
        for (int j = 0; j < 8; ++j) bfr[j] = f2bf(bbase[j * 128]);

        int col = ct * 16 + c16;
        int cs = col >> 5;                   // b_ (0..3)
        int s = col & 31;                    // r2 index
        for (int rt = 0; rt < 25; ++rt) {
            // A-frag: row R = rt*16 + c16 -> i1 = rt*4 + (c16>>2), a_ = c16&3
            const float* abase = core0 + (size_t)(rt * 4 + (c16 >> 2)) * 128
                                 + (c16 & 3) * 32 + h * 8;
            f32x4 x0 = *(const f32x4*)abase;
            f32x4 x1 = *(const f32x4*)(abase + 4);
            short8v afr;
#pragma unroll
            for (int j = 0; j < 4; ++j) { afr[j] = f2bf(x0[j]); afr[j + 4] = f2bf(x1[j]); }

            f32x4 d = __builtin_amdgcn_mfma_f32_16x16x32_bf16(
                afr, bfr, (f32x4){0.f, 0.f, 0.f, 0.f}, 0, 0, 0);

            // D row = h*4 + q; i1 = rt*4 + h, a_ = q -> m = q*4 + cs,
            // half = m>>3, row-in-half = m&7.
            int pair = (rt * 4 + h) * P1 + i2;
#pragma unroll
            for (int q = 0; q < 4; ++q) {
                int m = q * 4 + cs;
                __hip_bfloat16* tbl = (m & 8) ? ab1 : ab0;
                tbl[(size_t)pair * 256 + (m & 7) * 32 + s] = __float2bfloat16(d[q]);
            }
        }
    }
}

// ---------------- K2: bag pooling via MFMA, 2-indices-per-MFMA, split tables ----
// 256 threads = 4 waves. bid -> g = bid>>3, xcd = bid&7; half = xcd>>2,
// sub = xcd&3; wave w handles bag = (g*4+sub)*4 + w, output rows m in
// [half*8, half*8+8).
__global__ __launch_bounds__(256) void bag_pool(const int* __restrict__ indices, int n,
                                                const int* __restrict__ offsets, int B,
                                                const char* __restrict__ ab0,
                                                const char* __restrict__ ab1,
                                                const char* __restrict__ bfrag,
                                                float* __restrict__ out) {
    int w = threadIdx.x >> 6;
    int lane = threadIdx.x & 63;
    int g = blockIdx.x >> 3;
    int xcd = blockIdx.x & 7;
    int half = xcd >> 2;
    int bag = (g * 4 + (xcd & 3)) * 4 + w;
    if (bag >= B) return;

    const char* tbl = half ? ab1 : ab0;

    int start = offsets[bag];
    int end = offsets[bag + 1];
    if (bag == B - 1 && end < n) end = n;   // jnp.repeat pads with last bag id
    if (end > n) end = n;
    if (start > n) start = n;
    if (end < start) end = start;
    int cnt = end - start;

    // per-lane fragment offsets
    int sel = (lane >> 3) & 1;                           // 0: idx j, 1: idx j+1
    int aoff = (lane & 7) * 64 + (lane >> 4) * 16;       // bytes within 512B row
    int boff = (lane >> 4) * 128 + (lane & 7) * 16;      // bytes within 512B row

    f32x4 acc0 = {0.f, 0.f, 0.f, 0.f};
    f32x4 acc1 = {0.f, 0.f, 0.f, 0.f};

    for (int cb = 0; cb < cnt; cb += 64) {
        int m = cnt - cb;
        if (m > 64) m = 64;
        unsigned idx = 0;
        if (lane < m) idx = (unsigned)indices[start + cb + lane];
        unsigned p = idx / 100u;                 // magic-mul
        unsigned i3 = idx - p * 100u;
        int abo = (int)(p << 9);                 // half-table row byte offset
        int bfo = (lane < m) ? (int)(i3 << 9) : NULL_BFO;

        int j = 0;
        // 2 pairs (4 indices, 2 MFMAs) per iteration
        for (; j + 3 < m; j += 4) {
            int A0 = __shfl(abo, j),     B0 = __shfl(bfo, j);
            int A1 = __shfl(abo, j + 1), B1 = __shfl(bfo, j + 1);
            int A2 = __shfl(abo, j + 2), B2 = __shfl(bfo, j + 2);
            int A3 = __shfl(abo, j + 3), B3 = __shfl(bfo, j + 3);
            int Ae = sel ? A1 : A0, Be = sel ? B1 : B0;
            int Af = sel ? A3 : A2, Bf = sel ? B3 : B2;
            short8v a0 = *(const short8v*)(tbl + Ae + aoff);
            short8v b0 = *(const short8v*)(bfrag + Be + boff);
            short8v a1 = *(const short8v*)(tbl + Af + aoff);
            short8v b1 = *(const short8v*)(bfrag + Bf + boff);
            acc0 = __builtin_amdgcn_mfma_f32_16x16x32_bf16(a0, b0, acc0, 0, 0, 0);
            acc1 = __builtin_amdgcn_mfma_f32_16x16x32_bf16(a1, b1, acc1, 0, 0, 0);
        }
        for (; j < m; j += 2) {
            // pair (j, j+1); if j+1 == m, lane m holds NULL_BFO -> Q2 adds zero
            int A0 = __shfl(abo, j),     B0 = __shfl(bfo, j);
            int A1 = __shfl(abo, j + 1), B1 = __shfl(bfo, j + 1);
            int Ae = sel ? A1 : A0, Be = sel ? B1 : B0;
            short8v a0 = *(const short8v*)(tbl + Ae + aoff);
            short8v b0 = *(const short8v*)(bfrag + Be + boff);
            acc0 = __builtin_amdgcn_mfma_f32_16x16x32_bf16(a0, b0, acc0, 0, 0, 0);
        }
    }
    f32x4 acc = acc0 + acc1;

    // Valid quadrants: Q1 = rows(l>>4 in {0,1}) x cols(l&15 < 8) -> idx even;
    // Q2 = rows(l>>4 in {2,3}) x cols >= 8 -> idx odd. Q2 lane = Q1 lane + 40.
#pragma unroll
    for (int q = 0; q < 4; ++q) {
        float o = __shfl(acc[q], (lane + 40) & 63);
        acc[q] += o;                          // valid only on Q1 lanes
    }
    int hi = lane >> 4, c3 = lane & 15;
    if (hi < 2 && c3 < 8) {
        float* obase = out + (size_t)bag * DIM;
#pragma unroll
        for (int q = 0; q < 4; ++q) {
            int d = (half * 8 + hi * 4 + q) * 8 + c3;
            atomicAdd(obase + d, acc[q]);
        }
    }
}

// ---------------- fallback (ws too small): direct VALU, equal-length bags ----------------
__global__ __launch_bounds__(128) void fallback_pool(const int* __restrict__ indices,
                                                     int n, int B,
                                                     const float* __restrict__ core0,
                                                     const float* __restrict__ core1,
                                                     const float* __restrict__ core2,
                                                     float* __restrict__ out) {
    int bag = blockIdx.x;
    int d = threadIdx.x;
    int m = d >> 3, c3 = d & 7;
    int a_ = m >> 2, b_ = m & 3;
    int H = n / B;
    float acc = 0.f;
    for (int j = bag * H; j < (bag + 1) * H; ++j) {
        int idx = indices[j];
        int i1 = idx / (P1 * P2);
        int rem = idx - i1 * (P1 * P2);
        int i2 = rem / P2;
        int i3 = rem - i2 * P2;
        const float* a = core0 + (size_t)i1 * 128;
        const float* b = core1 + (size_t)i2 * 4096;
        const float* c = core2 + (size_t)i3 * 256;
        float e = 0.f;
        for (int s = 0; s < 32; ++s) {
            float abv = 0.f;
            for (int r = 0; r < 32; ++r)
                abv += a[a_ * 32 + r] * b[r * 128 + b_ * 32 + s];
            e += abv * c[s * 8 + c3];
        }
        acc += e;
    }
    out[(size_t)bag * DIM + d] = acc;
}

extern "C" void kernel_launch(void* const* d_in, const int* in_sizes, int n_in,
                              void* d_out, int out_size, void* d_ws, size_t ws_size,
                              hipStream_t stream) {
    const int* indices = (const int*)d_in[0];
    const int* lengths = (const int*)d_in[1];
    const float* core0 = (const float*)d_in[2];
    const float* core1 = (const float*)d_in[3];
    const float* core2 = (const float*)d_in[4];
    float* out = (float*)d_out;
    int n = in_sizes[0];
    int B = in_sizes[1];

    const size_t OFF_OFFSETS = 0;                            // (B+1) ints
    const size_t OFF_BFRAG = 32768;                          // 101 * 512 B
    const size_t OFF_AB0 = 131072;                           // 10000 * 512 B
    const size_t OFF_AB1 = OFF_AB0 + (size_t)NPAIR * 512;
    const size_t REQ = OFF_AB1 + (size_t)NPAIR * 512;

    if (ws_size >= REQ) {
        int* offsets = (int*)((char*)d_ws + OFF_OFFSETS);
        __hip_bfloat16* bfragp = (__hip_bfloat16*)((char*)d_ws + OFF_BFRAG);
        __hip_bfloat16* abt0 = (__hip_bfloat16*)((char*)d_ws + OFF_AB0);
        __hip_bfloat16* abt1 = (__hip_bfloat16*)((char*)d_ws + OFF_AB1);

        hipMemsetAsync(d_out, 0, (size_t)out_size * sizeof(float), stream);
        prep<<<1 + P2 + 200, 256, 0, stream>>>(lengths, B, core0, core1, core2,
                                               offsets, bfragp, abt0, abt1);
        int grid = ((B + 15) / 16) * 8;
        bag_pool<<<grid, 256, 0, stream>>>(indices, n, offsets, B,
                                           (const char*)abt0, (const char*)abt1,
                                           (const char*)bfragp, out);
    } else {
        fallback_pool<<<B, 128, 0, stream>>>(indices, n, B, core0, core1, core2, out);
    }
}